// Round 2
// baseline (123481.250 us; speedup 1.0000x reference)
//
#include <hip/hip_runtime.h>
#include <hip/hip_cooperative_groups.h>
#include <cmath>

namespace cg = cooperative_groups;

constexpr int Bn = 16;
constexpr int Tn = 1024;
constexpr int Hn = 1024;
constexpr int Gn = 4096;   // 4*H
constexpr int TC = 128;    // time-chunk length
constexpr int NCH = Tn / TC;

// LDS gap-pad: +4-float gap every 32 floats (breaks 4-way fragment conflicts)
__device__ __forceinline__ int padc(int c) { return c + ((c >> 5) << 2); }

// ---------------------------------------------------------------------------
// Chunked GEMM: xpc[mc][g] = sum_k A[arow(mc)][k] * Wm[g][k] + bias[g]
// mc = by*128 + r  (= b*TC + tc);  arow = by*ABS + AT0 + r.
//   layer 1: A = x      [B*Tn][1024], ABS = Tn,  AT0 = chunk*TC
//   layer 2: A = hseqc  [B*TC][1024], ABS = TC,  AT0 = 0
// fp32, BM=BN=128, BK=16, 256 threads, 8x8 microtile, register prefetch.
__global__ __launch_bounds__(256)
void gemm_xw(const float* __restrict__ A, const float* __restrict__ Wm,
             const float* __restrict__ bias, float* __restrict__ xpc,
             int ABS, int AT0)
{
    __shared__ float As[16 * 144];
    __shared__ float Bs[16 * 144];

    const int tid = threadIdx.x;
    const int n0 = blockIdx.x * 128;
    const int m0 = blockIdx.y * 128;
    const int r0 = tid >> 2;        // 0..63 (+64 for 2nd load)
    const int kq = tid & 3;         // which float4 of the 16-wide k slab
    const int tx = tid & 15, ty = tid >> 4;
    const int txp = tx * 8 + ((tx >> 2) << 2);
    const int typ = ty * 8 + ((ty >> 2) << 2);

    const int arow0 = blockIdx.y * ABS + AT0 + r0;       // rows are contiguous
    const int arow1 = arow0 + 64;

    float acc[8][8];
#pragma unroll
    for (int i = 0; i < 8; ++i)
#pragma unroll
        for (int j = 0; j < 8; ++j) acc[i][j] = 0.f;

    const int pr0 = padc(r0), pr1 = padc(r0 + 64);

    float4 pa0, pa1, pb0, pb1;
    {
        pa0 = *(const float4*)(A  + (size_t)arow0 * Hn + kq * 4);
        pa1 = *(const float4*)(A  + (size_t)arow1 * Hn + kq * 4);
        pb0 = *(const float4*)(Wm + (size_t)(n0 + r0     ) * Hn + kq * 4);
        pb1 = *(const float4*)(Wm + (size_t)(n0 + r0 + 64) * Hn + kq * 4);
    }

    for (int kt = 0; kt < Hn / 16; ++kt) {
        __syncthreads();
        const int kr = kq * 4;
        As[(kr + 0) * 144 + pr0] = pa0.x;  As[(kr + 1) * 144 + pr0] = pa0.y;
        As[(kr + 2) * 144 + pr0] = pa0.z;  As[(kr + 3) * 144 + pr0] = pa0.w;
        As[(kr + 0) * 144 + pr1] = pa1.x;  As[(kr + 1) * 144 + pr1] = pa1.y;
        As[(kr + 2) * 144 + pr1] = pa1.z;  As[(kr + 3) * 144 + pr1] = pa1.w;
        Bs[(kr + 0) * 144 + pr0] = pb0.x;  Bs[(kr + 1) * 144 + pr0] = pb0.y;
        Bs[(kr + 2) * 144 + pr0] = pb0.z;  Bs[(kr + 3) * 144 + pr0] = pb0.w;
        Bs[(kr + 0) * 144 + pr1] = pb1.x;  Bs[(kr + 1) * 144 + pr1] = pb1.y;
        Bs[(kr + 2) * 144 + pr1] = pb1.z;  Bs[(kr + 3) * 144 + pr1] = pb1.w;
        __syncthreads();

        if (kt + 1 < Hn / 16) {
            const int ko = (kt + 1) * 16 + kq * 4;
            pa0 = *(const float4*)(A  + (size_t)arow0 * Hn + ko);
            pa1 = *(const float4*)(A  + (size_t)arow1 * Hn + ko);
            pb0 = *(const float4*)(Wm + (size_t)(n0 + r0     ) * Hn + ko);
            pb1 = *(const float4*)(Wm + (size_t)(n0 + r0 + 64) * Hn + ko);
        }

#pragma unroll
        for (int k = 0; k < 16; ++k) {
            const float4 a0 = *(const float4*)(&As[k * 144 + typ]);
            const float4 a1 = *(const float4*)(&As[k * 144 + typ + 4]);
            const float4 b0 = *(const float4*)(&Bs[k * 144 + txp]);
            const float4 b1 = *(const float4*)(&Bs[k * 144 + txp + 4]);
            const float a[8] = {a0.x, a0.y, a0.z, a0.w, a1.x, a1.y, a1.z, a1.w};
            const float b[8] = {b0.x, b0.y, b0.z, b0.w, b1.x, b1.y, b1.z, b1.w};
#pragma unroll
            for (int i = 0; i < 8; ++i)
#pragma unroll
                for (int j = 0; j < 8; ++j)
                    acc[i][j] = fmaf(a[i], b[j], acc[i][j]);
        }
    }

    const float4 bb0 = *(const float4*)(bias + n0 + tx * 8);
    const float4 bb1 = *(const float4*)(bias + n0 + tx * 8 + 4);
#pragma unroll
    for (int i = 0; i < 8; ++i) {
        float4 o0 = make_float4(acc[i][0] + bb0.x, acc[i][1] + bb0.y,
                                acc[i][2] + bb0.z, acc[i][3] + bb0.w);
        float4 o1 = make_float4(acc[i][4] + bb1.x, acc[i][5] + bb1.y,
                                acc[i][6] + bb1.z, acc[i][7] + bb1.w);
        float* dst = xpc + (size_t)(m0 + ty * 8 + i) * Gn + n0 + tx * 8;
        *(float4*)dst = o0;
        *(float4*)(dst + 4) = o1;
    }
}

// ---------------------------------------------------------------------------
// Cooperative chunked scan. 256 blocks x 256 threads, 1 block/CU (85 KB LDS).
// Block owns j0..j0+3: its 16 R rows live in LDS for the whole chunk.
// Per step: 8x8 register-tile FMA over k, 2-stage shfl_xor quad pre-reduce,
// LDS reduce over 16 quad-slices, gates on tid<64, h double-buffered in
// global, one grid.sync per step. State (c,n,m) carried in registers within
// a chunk, persisted to global between chunks.
constexpr int RS_FLOATS  = 256 * 17 * 4;   // 17408 (16 rows x 1024 k, padded)
constexpr int RED_FLOATS = 16 * 260;       // 4160
constexpr int SCAN_LDS_BYTES = (RS_FLOATS + RED_FLOATS + 256) * 4;  // 87296

__global__ __launch_bounds__(256)
void slstm_scan(const float* __restrict__ xpc,   // [B*TC][4096], mc = b*TC+tc
                const float* __restrict__ Rm,    // [4096][1024]
                float* __restrict__ hseqc,       // [B*TC][1024] or nullptr
                float* __restrict__ h0,
                float* __restrict__ h1,
                float* __restrict__ Cst, float* __restrict__ Nst,
                float* __restrict__ Mst, int first)
{
    extern __shared__ float smem[];
    float* Rs   = smem;                  // [256 kchunks][17 slots][4]
    float* red  = smem + RS_FLOATS;      // [16 slices][260]
    float* preS = red + RED_FLOATS;      // [256]

    const int tid = threadIdx.x;
    const int j0 = blockIdx.x * 4;

    // Stage 16 R rows (g = q*1024 + j0 + jj) k-major into LDS.
    for (int i = 0; i < 16; ++i) {
        const int g = (i >> 2) * 1024 + j0 + (i & 3);
        float4 v = *(const float4*)(Rm + (size_t)g * Hn + tid * 4);
        *(float4*)(&Rs[(tid * 17 + i) * 4]) = v;
    }
    __syncthreads();

    const int ksl = tid & 63;       // k-slice lane
    const int tt  = tid >> 6;       // wave id
    const int rh = tt & 1, bh = tt >> 1;
    const int qd = ksl >> 2, sub = ksl & 3;

    // reduce/gate ownership
    const int rb = tid & 15;        // b
    const int rr = tid >> 4;        // r (gate*4 + jj)
    const float* xptr = xpc + (size_t)(rb * TC) * Gn
                            + (rr >> 2) * 1024 + j0 + (rr & 3);

    float c_s = 0.f, n_s = 1.f, m_s = 0.f;
    if (!first && tid < 64) {
        const int b = tid & 15, j = j0 + (tid >> 4);
        c_s = Cst[b * Hn + j];
        n_s = Nst[b * Hn + j];
        m_s = Mst[b * Hn + j];
    }

    cg::grid_group grid = cg::this_grid();

    for (int tc = 0; tc < TC; ++tc) {
        const float* hc = (tc & 1) ? h1 : h0;
        float*       hn = (tc & 1) ? h0 : h1;

        const float xval = xptr[(size_t)tc * Gn];   // hoisted: hides under FMA

        float acc[8][8];
#pragma unroll
        for (int i = 0; i < 8; ++i)
#pragma unroll
            for (int j = 0; j < 8; ++j) acc[i][j] = 0.f;

#pragma unroll 2
        for (int c4 = 0; c4 < 4; ++c4) {
            const int kc = ksl + 64 * c4;   // interleaved k-chunks: coalesced
            const int kb = kc * 4;
            float4 hv[8], rv[8];
#pragma unroll
            for (int i = 0; i < 8; ++i)
                hv[i] = *(const float4*)(hc + (size_t)(bh * 8 + i) * Hn + kb);
#pragma unroll
            for (int i = 0; i < 8; ++i)
                rv[i] = *(const float4*)(&Rs[(kc * 17 + rh * 8 + i) * 4]);
#pragma unroll
            for (int i2 = 0; i2 < 8; ++i2)
#pragma unroll
                for (int i = 0; i < 8; ++i) {
                    acc[i2][i] = fmaf(rv[i2].x, hv[i].x, acc[i2][i]);
                    acc[i2][i] = fmaf(rv[i2].y, hv[i].y, acc[i2][i]);
                    acc[i2][i] = fmaf(rv[i2].z, hv[i].z, acc[i2][i]);
                    acc[i2][i] = fmaf(rv[i2].w, hv[i].w, acc[i2][i]);
                }
        }

        // quad butterfly: every lane gets its quad's partial sum (DPP adds)
#pragma unroll
        for (int i2 = 0; i2 < 8; ++i2)
#pragma unroll
            for (int i = 0; i < 8; ++i) {
                float v = acc[i2][i];
                v += __shfl_xor(v, 1);
                v += __shfl_xor(v, 2);
                acc[i2][i] = v;
            }

        // lane (qd*4+sub) writes rows i2 in {2sub, 2sub+1}; static acc index
#pragma unroll
        for (int i2 = 0; i2 < 8; ++i2) {
            if ((i2 >> 1) == sub) {
                const int o = (rh * 8 + i2) * 16 + bh * 8;
                *(float4*)(&red[qd * 260 + o]) =
                    make_float4(acc[i2][0], acc[i2][1], acc[i2][2], acc[i2][3]);
                *(float4*)(&red[qd * 260 + o + 4]) =
                    make_float4(acc[i2][4], acc[i2][5], acc[i2][6], acc[i2][7]);
            }
        }
        __syncthreads();

        // final reduce over 16 quad-slices; thread tid owns output o = tid
        {
            float s0 = 0.f, s1 = 0.f, s2 = 0.f, s3 = 0.f;
#pragma unroll
            for (int k2 = 0; k2 < 16; k2 += 4) {
                s0 += red[(k2 + 0) * 260 + tid];
                s1 += red[(k2 + 1) * 260 + tid];
                s2 += red[(k2 + 2) * 260 + tid];
                s3 += red[(k2 + 3) * 260 + tid];
            }
            preS[tid] = (s0 + s1) + (s2 + s3) + xval;
        }
        __syncthreads();

        if (tid < 64) {
            const int b = tid & 15, jj = tid >> 4;
            const float pz = preS[(jj     ) * 16 + b];
            const float pi = preS[(4  + jj) * 16 + b];
            const float pf = preS[(8  + jj) * 16 + b];
            const float po = preS[(12 + jj) * 16 + b];
            const float z  = tanhf(pz);
            const float og = 1.f / (1.f + expf(-po));
            const float mn = fmaxf(pf + m_s, pi);
            const float ip = expf(pi - mn);
            const float fp = expf(pf + m_s - mn);
            c_s = fp * c_s + ip * z;
            n_s = fp * n_s + ip;
            m_s = mn;
            const float hnew = og * (c_s / n_s);
            const int j = j0 + jj;
            hn[b * Hn + j] = hnew;
            if (hseqc) hseqc[(size_t)(b * TC + tc) * Hn + j] = hnew;
        }
        __threadfence();
        grid.sync();
    }

    if (tid < 64) {
        const int b = tid & 15, j = j0 + (tid >> 4);
        Cst[b * Hn + j] = c_s;
        Nst[b * Hn + j] = n_s;
        Mst[b * Hn + j] = m_s;
    }
}

// ---------------------------------------------------------------------------
__global__ __launch_bounds__(256)
void out_head(const float* __restrict__ hl, const float* __restrict__ Wo,
              const float* __restrict__ bo, float* __restrict__ out)
{
    const int tid = threadIdx.x;
    const int b = tid & 15;
    const int n = blockIdx.x * 16 + (tid >> 4);
    float s0 = 0.f, s1 = 0.f;
    for (int k = 0; k < Hn; k += 8) {
        float4 hv0 = *(const float4*)(hl + b * Hn + k);
        float4 hv1 = *(const float4*)(hl + b * Hn + k + 4);
        float4 wv0 = *(const float4*)(Wo + (size_t)n * Hn + k);
        float4 wv1 = *(const float4*)(Wo + (size_t)n * Hn + k + 4);
        s0 += hv0.x * wv0.x + hv0.y * wv0.y + hv0.z * wv0.z + hv0.w * wv0.w;
        s1 += hv1.x * wv1.x + hv1.y * wv1.y + hv1.z * wv1.z + hv1.w * wv1.w;
    }
    out[b * 1024 + n] = s0 + s1 + bo[n];
}

// ---------------------------------------------------------------------------
extern "C" void kernel_launch(void* const* d_in, const int* in_sizes, int n_in,
                              void* d_out, int out_size, void* d_ws, size_t ws_size,
                              hipStream_t stream)
{
    const float* x  = (const float*)d_in[0];   // [16][1024][1024]
    const float* W  = (const float*)d_in[1];   // [2][4096][1024]
    const float* R  = (const float*)d_in[2];   // [2][4096][1024]
    const float* bb = (const float*)d_in[3];   // [2][4096]
    const float* Wo = (const float*)d_in[4];   // [1024][1024]
    const float* bo = (const float*)d_in[5];   // [1024]
    float* out = (float*)d_out;
    (void)in_sizes; (void)n_in; (void)out_size; (void)ws_size;

    // workspace layout (fp32) — total ~40.6 MB
    float* ws    = (float*)d_ws;
    float* xpc   = ws;                               // 16*TC*4096 = 8,388,608
    float* hseqc = xpc + (size_t)Bn * TC * Gn;       // 16*TC*1024 = 2,097,152
    float* hbuf  = hseqc + (size_t)Bn * TC * Hn;     // 4 * 16384 (h0/h1 x 2 layers)
    float* stC   = hbuf + 4 * 16384;                 // 2 * 16384
    float* stN   = stC + 2 * 16384;
    float* stM   = stN + 2 * 16384;

    hipFuncSetAttribute(reinterpret_cast<const void*>(slstm_scan),
                        hipFuncAttributeMaxDynamicSharedMemorySize, SCAN_LDS_BYTES);

    hipMemsetAsync(hbuf, 0, 4 * 16384 * sizeof(float), stream);  // h(t=0) = 0

    for (int ch = 0; ch < NCH; ++ch) {
        for (int l = 0; l < 2; ++l) {
            const float* Al  = (l == 0) ? x : hseqc;
            const int    ABS = (l == 0) ? Tn : TC;
            const int    AT0 = (l == 0) ? ch * TC : 0;
            const float* Wl = W + (size_t)l * Gn * Hn;
            const float* Rl = R + (size_t)l * Gn * Hn;
            const float* bl = bb + l * Gn;

            hipLaunchKernelGGL(gemm_xw, dim3(32, 16), dim3(256), 0, stream,
                               Al, Wl, bl, xpc, ABS, AT0);

            float* h0 = hbuf + l * 2 * 16384;
            float* h1 = h0 + 16384;
            float* Cs = stC + l * 16384;
            float* Ns = stN + l * 16384;
            float* Ms = stM + l * 16384;
            const float* xpa = xpc;
            float* hs = (l == 0) ? hseqc : nullptr;
            int first = (ch == 0) ? 1 : 0;
            void* args[] = { (void*)&xpa, (void*)&Rl, (void*)&hs,
                             (void*)&h0, (void*)&h1,
                             (void*)&Cs, (void*)&Ns, (void*)&Ms, (void*)&first };
            hipLaunchCooperativeKernel(reinterpret_cast<const void*>(slstm_scan),
                                       dim3(256), dim3(256), args,
                                       SCAN_LDS_BYTES, stream);
        }
    }

    hipLaunchKernelGGL(out_head, dim3(64), dim3(256), 0, stream,
                       hbuf + 2 * 16384, Wo, bo, out);
}

// Round 3
// 48782.504 us; speedup vs baseline: 2.5313x; 2.5313x over previous
//
#include <hip/hip_runtime.h>
#include <cmath>

constexpr int Bn = 16;
constexpr int Tn = 1024;
constexpr int Hn = 1024;
constexpr int Gn = 4096;   // 4*H
constexpr int TC = 128;    // time-chunk length
constexpr int NCH = Tn / TC;
constexpr int NBLK = 256;  // scan grid size (1 block/CU)

// LDS gap-pad: +4-float gap every 32 floats (breaks 4-way fragment conflicts)
__device__ __forceinline__ int padc(int c) { return c + ((c >> 5) << 2); }

// ---------------------------------------------------------------------------
// Chunked GEMM: xpc[mc][g] = sum_k A[arow(mc)][k] * Wm[g][k] + bias[g]
// (unchanged from round 2 — ~230 µs/dispatch, fp32 vector-bound)
__global__ __launch_bounds__(256)
void gemm_xw(const float* __restrict__ A, const float* __restrict__ Wm,
             const float* __restrict__ bias, float* __restrict__ xpc,
             int ABS, int AT0)
{
    __shared__ float As[16 * 144];
    __shared__ float Bs[16 * 144];

    const int tid = threadIdx.x;
    const int n0 = blockIdx.x * 128;
    const int m0 = blockIdx.y * 128;
    const int r0 = tid >> 2;
    const int kq = tid & 3;
    const int tx = tid & 15, ty = tid >> 4;
    const int txp = tx * 8 + ((tx >> 2) << 2);
    const int typ = ty * 8 + ((ty >> 2) << 2);

    const int arow0 = blockIdx.y * ABS + AT0 + r0;
    const int arow1 = arow0 + 64;

    float acc[8][8];
#pragma unroll
    for (int i = 0; i < 8; ++i)
#pragma unroll
        for (int j = 0; j < 8; ++j) acc[i][j] = 0.f;

    const int pr0 = padc(r0), pr1 = padc(r0 + 64);

    float4 pa0, pa1, pb0, pb1;
    {
        pa0 = *(const float4*)(A  + (size_t)arow0 * Hn + kq * 4);
        pa1 = *(const float4*)(A  + (size_t)arow1 * Hn + kq * 4);
        pb0 = *(const float4*)(Wm + (size_t)(n0 + r0     ) * Hn + kq * 4);
        pb1 = *(const float4*)(Wm + (size_t)(n0 + r0 + 64) * Hn + kq * 4);
    }

    for (int kt = 0; kt < Hn / 16; ++kt) {
        __syncthreads();
        const int kr = kq * 4;
        As[(kr + 0) * 144 + pr0] = pa0.x;  As[(kr + 1) * 144 + pr0] = pa0.y;
        As[(kr + 2) * 144 + pr0] = pa0.z;  As[(kr + 3) * 144 + pr0] = pa0.w;
        As[(kr + 0) * 144 + pr1] = pa1.x;  As[(kr + 1) * 144 + pr1] = pa1.y;
        As[(kr + 2) * 144 + pr1] = pa1.z;  As[(kr + 3) * 144 + pr1] = pa1.w;
        Bs[(kr + 0) * 144 + pr0] = pb0.x;  Bs[(kr + 1) * 144 + pr0] = pb0.y;
        Bs[(kr + 2) * 144 + pr0] = pb0.z;  Bs[(kr + 3) * 144 + pr0] = pb0.w;
        Bs[(kr + 0) * 144 + pr1] = pb1.x;  Bs[(kr + 1) * 144 + pr1] = pb1.y;
        Bs[(kr + 2) * 144 + pr1] = pb1.z;  Bs[(kr + 3) * 144 + pr1] = pb1.w;
        __syncthreads();

        if (kt + 1 < Hn / 16) {
            const int ko = (kt + 1) * 16 + kq * 4;
            pa0 = *(const float4*)(A  + (size_t)arow0 * Hn + ko);
            pa1 = *(const float4*)(A  + (size_t)arow1 * Hn + ko);
            pb0 = *(const float4*)(Wm + (size_t)(n0 + r0     ) * Hn + ko);
            pb1 = *(const float4*)(Wm + (size_t)(n0 + r0 + 64) * Hn + ko);
        }

#pragma unroll
        for (int k = 0; k < 16; ++k) {
            const float4 a0 = *(const float4*)(&As[k * 144 + typ]);
            const float4 a1 = *(const float4*)(&As[k * 144 + typ + 4]);
            const float4 b0 = *(const float4*)(&Bs[k * 144 + txp]);
            const float4 b1 = *(const float4*)(&Bs[k * 144 + txp + 4]);
            const float a[8] = {a0.x, a0.y, a0.z, a0.w, a1.x, a1.y, a1.z, a1.w};
            const float b[8] = {b0.x, b0.y, b0.z, b0.w, b1.x, b1.y, b1.z, b1.w};
#pragma unroll
            for (int i = 0; i < 8; ++i)
#pragma unroll
                for (int j = 0; j < 8; ++j)
                    acc[i][j] = fmaf(a[i], b[j], acc[i][j]);
        }
    }

    const float4 bb0 = *(const float4*)(bias + n0 + tx * 8);
    const float4 bb1 = *(const float4*)(bias + n0 + tx * 8 + 4);
#pragma unroll
    for (int i = 0; i < 8; ++i) {
        float4 o0 = make_float4(acc[i][0] + bb0.x, acc[i][1] + bb0.y,
                                acc[i][2] + bb0.z, acc[i][3] + bb0.w);
        float4 o1 = make_float4(acc[i][4] + bb1.x, acc[i][5] + bb1.y,
                                acc[i][6] + bb1.z, acc[i][7] + bb1.w);
        float* dst = xpc + (size_t)(m0 + ty * 8 + i) * Gn + n0 + tx * 8;
        *(float4*)dst = o0;
        *(float4*)(dst + 4) = o1;
    }
}

// ---------------------------------------------------------------------------
// Custom device-wide barrier: monotonic epoch counter, one atomic per block.
// Release fence (drain h stores, wbL2) -> arrive -> spin (AGENT-scope load,
// s_sleep backoff) -> acquire fence (invalidate) -> block barrier.
// Monotonic target => no reset race; double-buffered h tolerates 1-step skew.
__device__ __forceinline__ void gbar(unsigned* cnt, unsigned target)
{
    __syncthreads();
    if (threadIdx.x == 0) {
        __threadfence();   // release: h/hseq stores visible device-wide
        __hip_atomic_fetch_add(cnt, 1u, __ATOMIC_RELAXED,
                               __HIP_MEMORY_SCOPE_AGENT);
        while (__hip_atomic_load(cnt, __ATOMIC_RELAXED,
                                 __HIP_MEMORY_SCOPE_AGENT) < target) {
            __builtin_amdgcn_s_sleep(1);
        }
        __threadfence();   // acquire: invalidate stale cached h
    }
    __syncthreads();
}

// ---------------------------------------------------------------------------
// Cooperative chunked scan (structure unchanged from round 2; only the
// grid-wide barrier replaced with gbar).
constexpr int RS_FLOATS  = 256 * 17 * 4;   // 17408
constexpr int RED_FLOATS = 16 * 260;       // 4160
constexpr int SCAN_LDS_BYTES = (RS_FLOATS + RED_FLOATS + 256) * 4;  // 87296

__global__ __launch_bounds__(256)
void slstm_scan(const float* __restrict__ xpc,   // [B*TC][4096], mc = b*TC+tc
                const float* __restrict__ Rm,    // [4096][1024]
                float* __restrict__ hseqc,       // [B*TC][1024] or nullptr
                float* __restrict__ h0,
                float* __restrict__ h1,
                float* __restrict__ Cst, float* __restrict__ Nst,
                float* __restrict__ Mst, int first,
                unsigned* __restrict__ bar, int ep0)
{
    extern __shared__ float smem[];
    float* Rs   = smem;                  // [256 kchunks][17 slots][4]
    float* red  = smem + RS_FLOATS;      // [16 slices][260]
    float* preS = red + RED_FLOATS;      // [256]

    const int tid = threadIdx.x;
    const int j0 = blockIdx.x * 4;

    for (int i = 0; i < 16; ++i) {
        const int g = (i >> 2) * 1024 + j0 + (i & 3);
        float4 v = *(const float4*)(Rm + (size_t)g * Hn + tid * 4);
        *(float4*)(&Rs[(tid * 17 + i) * 4]) = v;
    }
    __syncthreads();

    const int ksl = tid & 63;
    const int tt  = tid >> 6;
    const int rh = tt & 1, bh = tt >> 1;
    const int qd = ksl >> 2, sub = ksl & 3;

    const int rb = tid & 15;
    const int rr = tid >> 4;
    const float* xptr = xpc + (size_t)(rb * TC) * Gn
                            + (rr >> 2) * 1024 + j0 + (rr & 3);

    float c_s = 0.f, n_s = 1.f, m_s = 0.f;
    if (!first && tid < 64) {
        const int b = tid & 15, j = j0 + (tid >> 4);
        c_s = Cst[b * Hn + j];
        n_s = Nst[b * Hn + j];
        m_s = Mst[b * Hn + j];
    }

    for (int tc = 0; tc < TC; ++tc) {
        const float* hc = (tc & 1) ? h1 : h0;
        float*       hn = (tc & 1) ? h0 : h1;

        const float xval = xptr[(size_t)tc * Gn];

        float acc[8][8];
#pragma unroll
        for (int i = 0; i < 8; ++i)
#pragma unroll
            for (int j = 0; j < 8; ++j) acc[i][j] = 0.f;

#pragma unroll 2
        for (int c4 = 0; c4 < 4; ++c4) {
            const int kc = ksl + 64 * c4;
            const int kb = kc * 4;
            float4 hv[8], rv[8];
#pragma unroll
            for (int i = 0; i < 8; ++i)
                hv[i] = *(const float4*)(hc + (size_t)(bh * 8 + i) * Hn + kb);
#pragma unroll
            for (int i = 0; i < 8; ++i)
                rv[i] = *(const float4*)(&Rs[(kc * 17 + rh * 8 + i) * 4]);
#pragma unroll
            for (int i2 = 0; i2 < 8; ++i2)
#pragma unroll
                for (int i = 0; i < 8; ++i) {
                    acc[i2][i] = fmaf(rv[i2].x, hv[i].x, acc[i2][i]);
                    acc[i2][i] = fmaf(rv[i2].y, hv[i].y, acc[i2][i]);
                    acc[i2][i] = fmaf(rv[i2].z, hv[i].z, acc[i2][i]);
                    acc[i2][i] = fmaf(rv[i2].w, hv[i].w, acc[i2][i]);
                }
        }

#pragma unroll
        for (int i2 = 0; i2 < 8; ++i2)
#pragma unroll
            for (int i = 0; i < 8; ++i) {
                float v = acc[i2][i];
                v += __shfl_xor(v, 1);
                v += __shfl_xor(v, 2);
                acc[i2][i] = v;
            }

#pragma unroll
        for (int i2 = 0; i2 < 8; ++i2) {
            if ((i2 >> 1) == sub) {
                const int o = (rh * 8 + i2) * 16 + bh * 8;
                *(float4*)(&red[qd * 260 + o]) =
                    make_float4(acc[i2][0], acc[i2][1], acc[i2][2], acc[i2][3]);
                *(float4*)(&red[qd * 260 + o + 4]) =
                    make_float4(acc[i2][4], acc[i2][5], acc[i2][6], acc[i2][7]);
            }
        }
        __syncthreads();

        {
            float s0 = 0.f, s1 = 0.f, s2 = 0.f, s3 = 0.f;
#pragma unroll
            for (int k2 = 0; k2 < 16; k2 += 4) {
                s0 += red[(k2 + 0) * 260 + tid];
                s1 += red[(k2 + 1) * 260 + tid];
                s2 += red[(k2 + 2) * 260 + tid];
                s3 += red[(k2 + 3) * 260 + tid];
            }
            preS[tid] = (s0 + s1) + (s2 + s3) + xval;
        }
        __syncthreads();

        if (tid < 64) {
            const int b = tid & 15, jj = tid >> 4;
            const float pz = preS[(jj     ) * 16 + b];
            const float pi = preS[(4  + jj) * 16 + b];
            const float pf = preS[(8  + jj) * 16 + b];
            const float po = preS[(12 + jj) * 16 + b];
            const float z  = tanhf(pz);
            const float og = 1.f / (1.f + expf(-po));
            const float mn = fmaxf(pf + m_s, pi);
            const float ip = expf(pi - mn);
            const float fp = expf(pf + m_s - mn);
            c_s = fp * c_s + ip * z;
            n_s = fp * n_s + ip;
            m_s = mn;
            const float hnew = og * (c_s / n_s);
            const int j = j0 + jj;
            hn[b * Hn + j] = hnew;
            if (hseqc) hseqc[(size_t)(b * TC + tc) * Hn + j] = hnew;
        }

        gbar(bar, (unsigned)(ep0 + tc + 1) * NBLK);
    }

    if (tid < 64) {
        const int b = tid & 15, j = j0 + (tid >> 4);
        Cst[b * Hn + j] = c_s;
        Nst[b * Hn + j] = n_s;
        Mst[b * Hn + j] = m_s;
    }
}

// ---------------------------------------------------------------------------
__global__ __launch_bounds__(256)
void out_head(const float* __restrict__ hl, const float* __restrict__ Wo,
              const float* __restrict__ bo, float* __restrict__ out)
{
    const int tid = threadIdx.x;
    const int b = tid & 15;
    const int n = blockIdx.x * 16 + (tid >> 4);
    float s0 = 0.f, s1 = 0.f;
    for (int k = 0; k < Hn; k += 8) {
        float4 hv0 = *(const float4*)(hl + b * Hn + k);
        float4 hv1 = *(const float4*)(hl + b * Hn + k + 4);
        float4 wv0 = *(const float4*)(Wo + (size_t)n * Hn + k);
        float4 wv1 = *(const float4*)(Wo + (size_t)n * Hn + k + 4);
        s0 += hv0.x * wv0.x + hv0.y * wv0.y + hv0.z * wv0.z + hv0.w * wv0.w;
        s1 += hv1.x * wv1.x + hv1.y * wv1.y + hv1.z * wv1.z + hv1.w * wv1.w;
    }
    out[b * 1024 + n] = s0 + s1 + bo[n];
}

// ---------------------------------------------------------------------------
extern "C" void kernel_launch(void* const* d_in, const int* in_sizes, int n_in,
                              void* d_out, int out_size, void* d_ws, size_t ws_size,
                              hipStream_t stream)
{
    const float* x  = (const float*)d_in[0];   // [16][1024][1024]
    const float* W  = (const float*)d_in[1];   // [2][4096][1024]
    const float* R  = (const float*)d_in[2];   // [2][4096][1024]
    const float* bb = (const float*)d_in[3];   // [2][4096]
    const float* Wo = (const float*)d_in[4];   // [1024][1024]
    const float* bo = (const float*)d_in[5];   // [1024]
    float* out = (float*)d_out;
    (void)in_sizes; (void)n_in; (void)out_size; (void)ws_size;

    // workspace layout (fp32) — total ~40.6 MB
    float* ws    = (float*)d_ws;
    float* xpc   = ws;                               // 16*TC*4096
    float* hseqc = xpc + (size_t)Bn * TC * Gn;       // 16*TC*1024
    float* hbuf  = hseqc + (size_t)Bn * TC * Hn;     // 4 * 16384
    float* stC   = hbuf + 4 * 16384;                 // 2 * 16384
    float* stN   = stC + 2 * 16384;
    float* stM   = stN + 2 * 16384;
    unsigned* bar = (unsigned*)(stM + 2 * 16384);    // 1 uint barrier counter

    hipFuncSetAttribute(reinterpret_cast<const void*>(slstm_scan),
                        hipFuncAttributeMaxDynamicSharedMemorySize, SCAN_LDS_BYTES);

    hipMemsetAsync(hbuf, 0, 4 * 16384 * sizeof(float), stream);  // h(t=0) = 0
    hipMemsetAsync(bar, 0, sizeof(unsigned), stream);            // barrier epoch 0

    for (int ch = 0; ch < NCH; ++ch) {
        for (int l = 0; l < 2; ++l) {
            const float* Al  = (l == 0) ? x : hseqc;
            const int    ABS = (l == 0) ? Tn : TC;
            const int    AT0 = (l == 0) ? ch * TC : 0;
            const float* Wl = W + (size_t)l * Gn * Hn;
            const float* Rl = R + (size_t)l * Gn * Hn;
            const float* bl = bb + l * Gn;

            hipLaunchKernelGGL(gemm_xw, dim3(32, 16), dim3(256), 0, stream,
                               Al, Wl, bl, xpc, ABS, AT0);

            float* h0 = hbuf + l * 2 * 16384;
            float* h1 = h0 + 16384;
            float* Cs = stC + l * 16384;
            float* Ns = stN + l * 16384;
            float* Ms = stM + l * 16384;
            const float* xpa = xpc;
            float* hs = (l == 0) ? hseqc : nullptr;
            int first = (ch == 0) ? 1 : 0;
            int ep0 = (ch * 2 + l) * TC;
            void* args[] = { (void*)&xpa, (void*)&Rl, (void*)&hs,
                             (void*)&h0, (void*)&h1,
                             (void*)&Cs, (void*)&Ns, (void*)&Ms, (void*)&first,
                             (void*)&bar, (void*)&ep0 };
            hipLaunchCooperativeKernel(reinterpret_cast<const void*>(slstm_scan),
                                       dim3(256), dim3(256), args,
                                       SCAN_LDS_BYTES, stream);
        }
    }

    hipLaunchKernelGGL(out_head, dim3(64), dim3(256), 0, stream,
                       hbuf + 2 * 16384, Wo, bo, out);
}

// Round 4
// 17721.252 us; speedup vs baseline: 6.9680x; 2.7528x over previous
//
#include <hip/hip_runtime.h>
#include <cmath>

constexpr int Bn = 16;
constexpr int Tn = 1024;
constexpr int Hn = 1024;
constexpr int Gn = 4096;   // 4*H
constexpr int TC = 128;    // time-chunk length
constexpr int NCH = Tn / TC;
constexpr int NBLK = 256;  // scan grid size (1 block/CU)
constexpr int HSLOT = Bn * Hn;   // 16384 floats per h ring slot

// LDS gap-pad: +4-float gap every 32 floats (breaks 4-way fragment conflicts)
__device__ __forceinline__ int padc(int c) { return c + ((c >> 5) << 2); }

// ---------------------------------------------------------------------------
// Chunked GEMM: xpc[mc][g] = sum_k A[arow(mc)][k] * Wm[g][k] + bias[g]
// (unchanged — ~230 µs/dispatch, fp32 vector-bound)
__global__ __launch_bounds__(256)
void gemm_xw(const float* __restrict__ A, const float* __restrict__ Wm,
             const float* __restrict__ bias, float* __restrict__ xpc,
             int ABS, int AT0)
{
    __shared__ float As[16 * 144];
    __shared__ float Bs[16 * 144];

    const int tid = threadIdx.x;
    const int n0 = blockIdx.x * 128;
    const int m0 = blockIdx.y * 128;
    const int r0 = tid >> 2;
    const int kq = tid & 3;
    const int tx = tid & 15, ty = tid >> 4;
    const int txp = tx * 8 + ((tx >> 2) << 2);
    const int typ = ty * 8 + ((ty >> 2) << 2);

    const int arow0 = blockIdx.y * ABS + AT0 + r0;
    const int arow1 = arow0 + 64;

    float acc[8][8];
#pragma unroll
    for (int i = 0; i < 8; ++i)
#pragma unroll
        for (int j = 0; j < 8; ++j) acc[i][j] = 0.f;

    const int pr0 = padc(r0), pr1 = padc(r0 + 64);

    float4 pa0, pa1, pb0, pb1;
    {
        pa0 = *(const float4*)(A  + (size_t)arow0 * Hn + kq * 4);
        pa1 = *(const float4*)(A  + (size_t)arow1 * Hn + kq * 4);
        pb0 = *(const float4*)(Wm + (size_t)(n0 + r0     ) * Hn + kq * 4);
        pb1 = *(const float4*)(Wm + (size_t)(n0 + r0 + 64) * Hn + kq * 4);
    }

    for (int kt = 0; kt < Hn / 16; ++kt) {
        __syncthreads();
        const int kr = kq * 4;
        As[(kr + 0) * 144 + pr0] = pa0.x;  As[(kr + 1) * 144 + pr0] = pa0.y;
        As[(kr + 2) * 144 + pr0] = pa0.z;  As[(kr + 3) * 144 + pr0] = pa0.w;
        As[(kr + 0) * 144 + pr1] = pa1.x;  As[(kr + 1) * 144 + pr1] = pa1.y;
        As[(kr + 2) * 144 + pr1] = pa1.z;  As[(kr + 3) * 144 + pr1] = pa1.w;
        Bs[(kr + 0) * 144 + pr0] = pb0.x;  Bs[(kr + 1) * 144 + pr0] = pb0.y;
        Bs[(kr + 2) * 144 + pr0] = pb0.z;  Bs[(kr + 3) * 144 + pr0] = pb0.w;
        Bs[(kr + 0) * 144 + pr1] = pb1.x;  Bs[(kr + 1) * 144 + pr1] = pb1.y;
        Bs[(kr + 2) * 144 + pr1] = pb1.z;  Bs[(kr + 3) * 144 + pr1] = pb1.w;
        __syncthreads();

        if (kt + 1 < Hn / 16) {
            const int ko = (kt + 1) * 16 + kq * 4;
            pa0 = *(const float4*)(A  + (size_t)arow0 * Hn + ko);
            pa1 = *(const float4*)(A  + (size_t)arow1 * Hn + ko);
            pb0 = *(const float4*)(Wm + (size_t)(n0 + r0     ) * Hn + ko);
            pb1 = *(const float4*)(Wm + (size_t)(n0 + r0 + 64) * Hn + ko);
        }

#pragma unroll
        for (int k = 0; k < 16; ++k) {
            const float4 a0 = *(const float4*)(&As[k * 144 + typ]);
            const float4 a1 = *(const float4*)(&As[k * 144 + typ + 4]);
            const float4 b0 = *(const float4*)(&Bs[k * 144 + txp]);
            const float4 b1 = *(const float4*)(&Bs[k * 144 + txp + 4]);
            const float a[8] = {a0.x, a0.y, a0.z, a0.w, a1.x, a1.y, a1.z, a1.w};
            const float b[8] = {b0.x, b0.y, b0.z, b0.w, b1.x, b1.y, b1.z, b1.w};
#pragma unroll
            for (int i = 0; i < 8; ++i)
#pragma unroll
                for (int j = 0; j < 8; ++j)
                    acc[i][j] = fmaf(a[i], b[j], acc[i][j]);
        }
    }

    const float4 bb0 = *(const float4*)(bias + n0 + tx * 8);
    const float4 bb1 = *(const float4*)(bias + n0 + tx * 8 + 4);
#pragma unroll
    for (int i = 0; i < 8; ++i) {
        float4 o0 = make_float4(acc[i][0] + bb0.x, acc[i][1] + bb0.y,
                                acc[i][2] + bb0.z, acc[i][3] + bb0.w);
        float4 o1 = make_float4(acc[i][4] + bb1.x, acc[i][5] + bb1.y,
                                acc[i][6] + bb1.z, acc[i][7] + bb1.w);
        float* dst = xpc + (size_t)(m0 + ty * 8 + i) * Gn + n0 + tx * 8;
        *(float4*)dst = o0;
        *(float4*)(dst + 4) = o1;
    }
}

// ---------------------------------------------------------------------------
// Fence-free agent-scope helpers (sc0/sc1 per-instruction coherence).
__device__ __forceinline__ void st_sc1(float* p, float v) {
    __hip_atomic_store(p, v, __ATOMIC_RELAXED, __HIP_MEMORY_SCOPE_AGENT);
}
__device__ __forceinline__ void st_sc1u(unsigned* p, unsigned v) {
    __hip_atomic_store(p, v, __ATOMIC_RELAXED, __HIP_MEMORY_SCOPE_AGENT);
}
__device__ __forceinline__ unsigned ld_sc1u(const unsigned* p) {
    return __hip_atomic_load(p, __ATOMIC_RELAXED, __HIP_MEMORY_SCOPE_AGENT);
}

// Flag barrier: per-block arrival slots + block-0 gather + go-word broadcast.
// No buffer_wbl2 / buffer_inv anywhere: h data moves via sc1 write-through
// stores (to L3) and fresh-address cached reads (ring buffer).
__device__ __forceinline__ void gbar2(unsigned* arr, unsigned* go, unsigned target)
{
    __syncthreads();                       // all compute + h stores issued
    const int tid = threadIdx.x;
    if (blockIdx.x == 0) {
        if (tid == 0) {
            asm volatile("s_waitcnt vmcnt(0)" ::: "memory");  // h at L3
            st_sc1u(&arr[0], target);
        }
        for (;;) {
            unsigned v = ld_sc1u(&arr[tid]);
            if (__syncthreads_and(v >= target)) break;
            __builtin_amdgcn_s_sleep(1);
        }
        if (tid == 0) st_sc1u(go, target);
        // no extra sync: gather already proved every block's h is at L3
    } else {
        if (tid == 0) {
            asm volatile("s_waitcnt vmcnt(0)" ::: "memory");  // h at L3
            st_sc1u(&arr[blockIdx.x], target);
            while (ld_sc1u(go) < target)
                __builtin_amdgcn_s_sleep(1);
        }
        __syncthreads();
    }
}

// ---------------------------------------------------------------------------
// Cooperative chunked scan; h exchanged through a TC-slot ring buffer.
// Step tc: read hring[tc] (normal cached float4), write h(tc+1) into
// hring[(tc+1)%TC] via sc1 stores. Slot 0 wraps to next chunk.
constexpr int RS_FLOATS  = 256 * 17 * 4;   // 17408
constexpr int RED_FLOATS = 16 * 260;       // 4160
constexpr int SCAN_LDS_BYTES = (RS_FLOATS + RED_FLOATS + 256) * 4;  // 87296

__global__ __launch_bounds__(256)
void slstm_scan(const float* __restrict__ xpc,   // [B*TC][4096], mc = b*TC+tc
                const float* __restrict__ Rm,    // [4096][1024]
                float* __restrict__ hseqc,       // [B*TC][1024] or nullptr
                float* __restrict__ hring,       // [TC][16][1024]
                float* __restrict__ Cst, float* __restrict__ Nst,
                float* __restrict__ Mst, int first,
                unsigned* __restrict__ arr, unsigned* __restrict__ go, int ep0)
{
    extern __shared__ float smem[];
    float* Rs   = smem;                  // [256 kchunks][17 slots][4]
    float* red  = smem + RS_FLOATS;      // [16 slices][260]
    float* preS = red + RED_FLOATS;      // [256]

    const int tid = threadIdx.x;
    const int j0 = blockIdx.x * 4;

    for (int i = 0; i < 16; ++i) {
        const int g = (i >> 2) * 1024 + j0 + (i & 3);
        float4 v = *(const float4*)(Rm + (size_t)g * Hn + tid * 4);
        *(float4*)(&Rs[(tid * 17 + i) * 4]) = v;
    }
    __syncthreads();

    const int ksl = tid & 63;
    const int tt  = tid >> 6;
    const int rh = tt & 1, bh = tt >> 1;
    const int qd = ksl >> 2, sub = ksl & 3;

    const int rb = tid & 15;
    const int rr = tid >> 4;
    const float* xptr = xpc + (size_t)(rb * TC) * Gn
                            + (rr >> 2) * 1024 + j0 + (rr & 3);

    float c_s = 0.f, n_s = 1.f, m_s = 0.f;
    if (!first && tid < 64) {
        const int b = tid & 15, j = j0 + (tid >> 4);
        c_s = Cst[b * Hn + j];
        n_s = Nst[b * Hn + j];
        m_s = Mst[b * Hn + j];
    }

    for (int tc = 0; tc < TC; ++tc) {
        const float* hc = hring + (size_t)tc * HSLOT;
        float*       hn = hring + (size_t)((tc + 1) & (TC - 1)) * HSLOT;

        const float xval = xptr[(size_t)tc * Gn];

        float acc[8][8];
#pragma unroll
        for (int i = 0; i < 8; ++i)
#pragma unroll
            for (int j = 0; j < 8; ++j) acc[i][j] = 0.f;

#pragma unroll 2
        for (int c4 = 0; c4 < 4; ++c4) {
            const int kc = ksl + 64 * c4;
            const int kb = kc * 4;
            float4 hv[8], rv[8];
#pragma unroll
            for (int i = 0; i < 8; ++i)
                hv[i] = *(const float4*)(hc + (size_t)(bh * 8 + i) * Hn + kb);
#pragma unroll
            for (int i = 0; i < 8; ++i)
                rv[i] = *(const float4*)(&Rs[(kc * 17 + rh * 8 + i) * 4]);
#pragma unroll
            for (int i2 = 0; i2 < 8; ++i2)
#pragma unroll
                for (int i = 0; i < 8; ++i) {
                    acc[i2][i] = fmaf(rv[i2].x, hv[i].x, acc[i2][i]);
                    acc[i2][i] = fmaf(rv[i2].y, hv[i].y, acc[i2][i]);
                    acc[i2][i] = fmaf(rv[i2].z, hv[i].z, acc[i2][i]);
                    acc[i2][i] = fmaf(rv[i2].w, hv[i].w, acc[i2][i]);
                }
        }

#pragma unroll
        for (int i2 = 0; i2 < 8; ++i2)
#pragma unroll
            for (int i = 0; i < 8; ++i) {
                float v = acc[i2][i];
                v += __shfl_xor(v, 1);
                v += __shfl_xor(v, 2);
                acc[i2][i] = v;
            }

#pragma unroll
        for (int i2 = 0; i2 < 8; ++i2) {
            if ((i2 >> 1) == sub) {
                const int o = (rh * 8 + i2) * 16 + bh * 8;
                *(float4*)(&red[qd * 260 + o]) =
                    make_float4(acc[i2][0], acc[i2][1], acc[i2][2], acc[i2][3]);
                *(float4*)(&red[qd * 260 + o + 4]) =
                    make_float4(acc[i2][4], acc[i2][5], acc[i2][6], acc[i2][7]);
            }
        }
        __syncthreads();

        {
            float s0 = 0.f, s1 = 0.f, s2 = 0.f, s3 = 0.f;
#pragma unroll
            for (int k2 = 0; k2 < 16; k2 += 4) {
                s0 += red[(k2 + 0) * 260 + tid];
                s1 += red[(k2 + 1) * 260 + tid];
                s2 += red[(k2 + 2) * 260 + tid];
                s3 += red[(k2 + 3) * 260 + tid];
            }
            preS[tid] = (s0 + s1) + (s2 + s3) + xval;
        }
        __syncthreads();

        if (tid < 64) {
            const int b = tid & 15, jj = tid >> 4;
            const float pz = preS[(jj     ) * 16 + b];
            const float pi = preS[(4  + jj) * 16 + b];
            const float pf = preS[(8  + jj) * 16 + b];
            const float po = preS[(12 + jj) * 16 + b];
            const float z  = tanhf(pz);
            const float og = 1.f / (1.f + expf(-po));
            const float mn = fmaxf(pf + m_s, pi);
            const float ip = expf(pi - mn);
            const float fp = expf(pf + m_s - mn);
            c_s = fp * c_s + ip * z;
            n_s = fp * n_s + ip;
            m_s = mn;
            const float hnew = og * (c_s / n_s);
            const int j = j0 + jj;
            st_sc1(&hn[b * Hn + j], hnew);                       // write-through
            if (hseqc) hseqc[(size_t)(b * TC + tc) * Hn + j] = hnew;
        }

        gbar2(arr, go, (unsigned)(ep0 + tc + 1));
    }

    if (tid < 64) {
        const int b = tid & 15, j = j0 + (tid >> 4);
        Cst[b * Hn + j] = c_s;
        Nst[b * Hn + j] = n_s;
        Mst[b * Hn + j] = m_s;
    }
}

// ---------------------------------------------------------------------------
__global__ __launch_bounds__(256)
void out_head(const float* __restrict__ hl, const float* __restrict__ Wo,
              const float* __restrict__ bo, float* __restrict__ out)
{
    const int tid = threadIdx.x;
    const int b = tid & 15;
    const int n = blockIdx.x * 16 + (tid >> 4);
    float s0 = 0.f, s1 = 0.f;
    for (int k = 0; k < Hn; k += 8) {
        float4 hv0 = *(const float4*)(hl + b * Hn + k);
        float4 hv1 = *(const float4*)(hl + b * Hn + k + 4);
        float4 wv0 = *(const float4*)(Wo + (size_t)n * Hn + k);
        float4 wv1 = *(const float4*)(Wo + (size_t)n * Hn + k + 4);
        s0 += hv0.x * wv0.x + hv0.y * wv0.y + hv0.z * wv0.z + hv0.w * wv0.w;
        s1 += hv1.x * wv1.x + hv1.y * wv1.y + hv1.z * wv1.z + hv1.w * wv1.w;
    }
    out[b * 1024 + n] = s0 + s1 + bo[n];
}

// ---------------------------------------------------------------------------
extern "C" void kernel_launch(void* const* d_in, const int* in_sizes, int n_in,
                              void* d_out, int out_size, void* d_ws, size_t ws_size,
                              hipStream_t stream)
{
    const float* x  = (const float*)d_in[0];   // [16][1024][1024]
    const float* W  = (const float*)d_in[1];   // [2][4096][1024]
    const float* R  = (const float*)d_in[2];   // [2][4096][1024]
    const float* bb = (const float*)d_in[3];   // [2][4096]
    const float* Wo = (const float*)d_in[4];   // [1024][1024]
    const float* bo = (const float*)d_in[5];   // [1024]
    float* out = (float*)d_out;
    (void)in_sizes; (void)n_in; (void)out_size; (void)ws_size;

    // workspace layout (fp32) — ~57 MB
    float* ws     = (float*)d_ws;
    float* xpc    = ws;                                  // 16*TC*4096 = 8.4M fl
    float* hseqc  = xpc + (size_t)Bn * TC * Gn;          // 16*TC*1024
    float* hring0 = hseqc + (size_t)Bn * TC * Hn;        // TC slots x 16384
    float* hring1 = hring0 + (size_t)TC * HSLOT;         // TC slots x 16384
    float* stC    = hring1 + (size_t)TC * HSLOT;         // 2 * 16384
    float* stN    = stC + 2 * 16384;
    float* stM    = stN + 2 * 16384;
    unsigned* arr = (unsigned*)(stM + 2 * 16384);        // 256 arrival slots
    unsigned* go  = arr + 256;                           // 1 go word

    hipFuncSetAttribute(reinterpret_cast<const void*>(slstm_scan),
                        hipFuncAttributeMaxDynamicSharedMemorySize, SCAN_LDS_BYTES);

    // h(t=0) = 0 for both layers (ring slot 0); reset barrier state.
    hipMemsetAsync(hring0, 0, HSLOT * sizeof(float), stream);
    hipMemsetAsync(hring1, 0, HSLOT * sizeof(float), stream);
    hipMemsetAsync(arr, 0, (256 + 1) * sizeof(unsigned), stream);

    for (int ch = 0; ch < NCH; ++ch) {
        for (int l = 0; l < 2; ++l) {
            const float* Al  = (l == 0) ? x : hseqc;
            const int    ABS = (l == 0) ? Tn : TC;
            const int    AT0 = (l == 0) ? ch * TC : 0;
            const float* Wl = W + (size_t)l * Gn * Hn;
            const float* Rl = R + (size_t)l * Gn * Hn;
            const float* bl = bb + l * Gn;

            hipLaunchKernelGGL(gemm_xw, dim3(32, 16), dim3(256), 0, stream,
                               Al, Wl, bl, xpc, ABS, AT0);

            float* hring = (l == 0) ? hring0 : hring1;
            float* Cs = stC + l * 16384;
            float* Ns = stN + l * 16384;
            float* Ms = stM + l * 16384;
            const float* xpa = xpc;
            float* hs = (l == 0) ? hseqc : nullptr;
            int first = (ch == 0) ? 1 : 0;
            int ep0 = (ch * 2 + l) * TC;
            void* args[] = { (void*)&xpa, (void*)&Rl, (void*)&hs,
                             (void*)&hring,
                             (void*)&Cs, (void*)&Ns, (void*)&Ms, (void*)&first,
                             (void*)&arr, (void*)&go, (void*)&ep0 };
            hipLaunchCooperativeKernel(reinterpret_cast<const void*>(slstm_scan),
                                       dim3(256), dim3(256), args,
                                       SCAN_LDS_BYTES, stream);
        }
    }

    // final h of layer 2 = hring1 slot 0 (written at tc = TC-1 of last chunk)
    hipLaunchKernelGGL(out_head, dim3(64), dim3(256), 0, stream,
                       hring1, Wo, bo, out);
}